// Round 4
// baseline (444.485 us; speedup 1.0000x reference)
//
#include <hip/hip_runtime.h>
#include <math.h>

// TokenRouter: LN(x) -> silu(x @ Wd^T) -> @ Wu^T -> top2 softmax
// H=2048, D=64, E=8, NTOK=16384, fp32 (no fp32 MFMA; bf16 flips top-2 picks).
//
// R4: weight-stationary / token-per-lane. R3 post-mortem showed the classic
// LDS-tiled form is LDS-BW-bound (2 B LDS per lane-FMA vs ~85 B/cyc/CU pipe
// => VALUBusy pinned at ~28%). Here:
//   - lane owns one token: acc[64] in VGPRs, x chunk in VGPRs (reused 64x)
//   - W addresses wave-uniform (wave id via readfirstlane => SGPR indices)
//     => compiler scalarizes W loads to s_load; fmac reads W from SGPR.
//     ZERO LDS / ZERO VMEM in the per-FMA path.
//   - K split 8 ways across waves (2048 waves = 2/SIMD), partials combined
//     in LDS once at the end.
//   - LN folded: dot_d = rstd*(A_d - mu*B_d) + C_d, A_d = sum x*gamma*W[d]
//     (gamma folded into x at consume), B/C block-redundant phase 0.
//   - X staged coalesced->LDS->per-lane row (wave-private buffer, no barrier).

#define H     2048
#define DBOT  64
#define NE    8
#define NWAVE 8             // K-split factor = waves per block
#define KSL   (H / NWAVE)   // 256 k per wave
#define KCH   32            // k per chunk (one 128B line per lane)
#define NCH   (KSL / KCH)   // 8
#define XPAD  33            // transpose row stride (odd => conflict-light)
#define RST   72            // reduction row stride (66 used)

__global__ __launch_bounds__(512) void router_kernel(
    const float* __restrict__ X,      // [ntok][H]
    const float* __restrict__ Wd,     // [DBOT][H]
    const float* __restrict__ Wu,     // [NE][DBOT]
    const float* __restrict__ gamma,  // [H]
    const float* __restrict__ beta,   // [H]
    float* __restrict__ out,          // [ntok][NE]
    const int ntok)
{
    __shared__ float Xs[NWAVE][64 * XPAD];   // 8 x 8448 B wave-private buffers
    __shared__ float red[64 * RST];          // per-token acc+stats combine
    __shared__ float BpS[DBOT][NWAVE + 1];
    __shared__ float CpS[DBOT][NWAVE + 1];
    __shared__ float BdS[DBOT], CdS[DBOT];
    __shared__ float wuS[NE * DBOT];

    const int tid  = threadIdx.x;
    const int lane = tid & 63;                                  // token within tile
    const int wv   = __builtin_amdgcn_readfirstlane(tid >> 6);  // K-slice, SGPR
    const long tok0 = (long)blockIdx.x * 64;

    if (tid < 128) ((float4*)wuS)[tid] = ((const float4*)Wu)[tid];

    // ---- Phase 0: B_d = sum_h gamma*W[d][h], C_d = sum_h beta*W[d][h]
    // thread (d = tid>>3, s = tid&7) sums its K-slice; reduce 8 partials.
    {
        const int d = tid >> 3;
        const int s = tid & 7;
        const float* wr = &Wd[d * H + s * KSL];
        const float* gr = &gamma[s * KSL];
        const float* br = &beta[s * KSL];
        float bp = 0.f, cp = 0.f;
        #pragma unroll 4
        for (int i = 0; i < KSL; i += 4) {
            const float4 w4 = *(const float4*)&wr[i];
            const float4 g4 = *(const float4*)&gr[i];
            const float4 b4 = *(const float4*)&br[i];
            bp += (w4.x*g4.x + w4.y*g4.y) + (w4.z*g4.z + w4.w*g4.w);
            cp += (w4.x*b4.x + w4.y*b4.y) + (w4.z*b4.z + w4.w*b4.w);
        }
        BpS[d][s] = bp; CpS[d][s] = cp;
    }
    __syncthreads();
    if (tid < DBOT) {
        float b = 0.f, c = 0.f;
        #pragma unroll
        for (int s = 0; s < NWAVE; ++s) { b += BpS[tid][s]; c += CpS[tid][s]; }
        BdS[tid] = b; CdS[tid] = c;
    }
    // visibility of BdS/CdS guaranteed by the combine barriers below

    // ---- Main: acc[d] = sum over this wave's K-slice of xg[k]*W[d][k]
    float acc[DBOT];
    #pragma unroll
    for (int d = 0; d < DBOT; ++d) acc[d] = 0.f;
    float xs = 0.f, xq = 0.f;

    float* xbuf = &Xs[wv][0];
    const int trow = lane >> 3;   // staging token sub-row
    const int tcol = lane & 7;    // staging float4 column

    for (int ch = 0; ch < NCH; ++ch) {
        const int kg = wv * KSL + ch * KCH;   // wave-uniform k origin

        // stage [64 tokens x 32 k] coalesced into wave-private LDS
        #pragma unroll
        for (int p = 0; p < 8; ++p) {
            const int t = trow + 8 * p;
            float4 v = make_float4(0.f, 0.f, 0.f, 0.f);
            if (tok0 + t < ntok)
                v = *(const float4*)&X[(tok0 + t) * (long)H + kg + 4 * tcol];
            *(float4*)&xbuf[t * XPAD + 4 * tcol] = v;
        }

        // transpose-read own token's 32 x values; raw stats; fold gamma
        float xt[KCH];
        #pragma unroll
        for (int q = 0; q < 8; ++q) {
            const float4 r = *(const float4*)&xbuf[lane * XPAD + 4 * q];
            xs += (r.x + r.y) + (r.z + r.w);
            xq += (r.x*r.x + r.y*r.y) + (r.z*r.z + r.w*r.w);
            const float4 g = *(const float4*)&gamma[kg + 4 * q];  // uniform
            xt[4*q+0] = r.x * g.x;
            xt[4*q+1] = r.y * g.y;
            xt[4*q+2] = r.z * g.z;
            xt[4*q+3] = r.w * g.w;
        }

        // 2048 fmac: W addresses uniform => s_load; x from VGPR; no LDS.
        const float* wb = &Wd[kg];
        #pragma unroll 16
        for (int d = 0; d < DBOT; ++d) {
            const float* wr = wb + d * H;
            float a = acc[d];
            #pragma unroll
            for (int q = 0; q < 8; ++q) {
                const float4 w4 = *(const float4*)&wr[4 * q];
                a += xt[4*q+0] * w4.x;
                a += xt[4*q+1] * w4.y;
                a += xt[4*q+2] * w4.z;
                a += xt[4*q+3] * w4.w;
            }
            acc[d] = a;
        }
    }

    // ---- Combine split-K partials + stats in LDS (serialized adds)
    __syncthreads();
    for (int w = 0; w < NWAVE; ++w) {
        if (wv == w) {
            float* r = &red[lane * RST];
            if (w == 0) {
                #pragma unroll
                for (int d = 0; d < DBOT; ++d) r[d] = acc[d];
                r[64] = xs; r[65] = xq;
            } else {
                #pragma unroll
                for (int d = 0; d < DBOT; ++d) r[d] += acc[d];
                r[64] += xs; r[65] += xq;
            }
        }
        __syncthreads();
    }

    // ---- Epilogue: LN-fold, silu, logits, top-2 softmax, store
    if (tid < 64 && tok0 + tid < ntok) {
        const float* r = &red[tid * RST];
        const float invH = 1.0f / (float)H;
        const float mu   = r[64] * invH;
        const float var  = r[65] * invH - mu * mu;
        const float rstd = 1.0f / sqrtf(var + 1e-5f);

        float lg[NE];
        #pragma unroll
        for (int e = 0; e < NE; ++e) lg[e] = 0.f;
        #pragma unroll 8
        for (int d = 0; d < DBOT; ++d) {
            const float t = rstd * (r[d] - mu * BdS[d]) + CdS[d];
            const float z = t / (1.0f + expf(-t));
            #pragma unroll
            for (int e = 0; e < NE; ++e) lg[e] += z * wuS[e * DBOT + d];
        }

        // top-2; strict > keeps lowest index on ties (matches lax.top_k)
        float v1 = -INFINITY, v2 = -INFINITY;
        int i1 = -1, i2 = -1;
        #pragma unroll
        for (int e = 0; e < NE; ++e) {
            const float v = lg[e];
            if (v > v1)      { v2 = v1; i2 = i1; v1 = v; i1 = e; }
            else if (v > v2) { v2 = v;  i2 = e; }
        }
        const float e2  = expf(v2 - v1);
        const float inv = 1.0f / (1.0f + e2);
        float o[NE];
        #pragma unroll
        for (int e = 0; e < NE; ++e)
            o[e] = (e == i1) ? inv : ((e == i2) ? e2 * inv : 0.0f);
        float4* op = (float4*)&out[(tok0 + tid) * NE];
        op[0] = make_float4(o[0], o[1], o[2], o[3]);
        op[1] = make_float4(o[4], o[5], o[6], o[7]);
    }
}

extern "C" void kernel_launch(void* const* d_in, const int* in_sizes, int n_in,
                              void* d_out, int out_size, void* d_ws, size_t ws_size,
                              hipStream_t stream) {
    const float* X     = (const float*)d_in[0];
    const float* Wd    = (const float*)d_in[1];
    const float* Wu    = (const float*)d_in[2];
    const float* gamma = (const float*)d_in[3];
    const float* beta  = (const float*)d_in[4];
    float* out = (float*)d_out;

    const int ntok = in_sizes[0] / H;            // 16384
    const int nblk = (ntok + 63) / 64;           // 256

    hipLaunchKernelGGL(router_kernel, dim3(nblk), dim3(512), 0, stream,
                       X, Wd, Wu, gamma, beta, out, ntok);
}

// Round 5
// 317.345 us; speedup vs baseline: 1.4006x; 1.4006x over previous
//
#include <hip/hip_runtime.h>
#include <math.h>

// TokenRouter: LN(x) -> silu(x @ Wd^T) -> @ Wu^T -> top2 softmax
// H=2048, D=64, E=8, NTOK=16384, fp32 in/out.
//
// R5: MFMA bf16x3. fp32 x,w split as hi+lo bf16; x*w ~= xh*wh + xh*wl + xl*wh
// (3 chained 16x16x32 bf16 MFMAs into one fp32 acc). Dropped xl*wl term is
// ~1.5e-5 relative => logit error ~2e-6, far below observed top-2 gaps.
// LN folded: dot_d = rstd*(A_d - mu*B_d) + C_d; A_d via MFMA on (x, gamma*W).
//
// Block: 64 tokens, 256 thr = 4 waves, K-split 4 (wave-private 512-k slice,
// no barriers in main loop). Per wave: 4x4 tiles of 16x16x32 => 64x64 C.
// Staging: fp32 global -> convert -> LDS rows [64][4 groups x (hi8|lo8)],
// row stride 144 B (2-way bank aliasing = free). mu/var inline at X staging;
// B_d/C_d in phase 0. R4 lesson: ALL register arrays indexed by fully
// unrolled constant loops only.

#define H     2048
#define DBOT  64
#define NE    8
#define NWAVE 4
#define KSL   (H / NWAVE)     // 512 k per wave
#define KC    32              // k per chunk = one MFMA-K
#define NCH   (KSL / KC)      // 16
#define ROWS  72              // shorts per LDS row (144 B; 64 data + pad)
#define WVBUF (64 * ROWS)     // shorts per buffer
#define RST   68              // fp32 combine row stride

typedef short  bf16x8 __attribute__((ext_vector_type(8)));
typedef float  f32x4  __attribute__((ext_vector_type(4)));

__device__ __forceinline__ unsigned short bf16rne(float x) {
    unsigned u = __float_as_uint(x);
    return (unsigned short)((u + 0x7FFFu + ((u >> 16) & 1u)) >> 16);
}
__device__ __forceinline__ float bf16tof(unsigned short h) {
    return __uint_as_float(((unsigned)h) << 16);
}

__global__ __launch_bounds__(256) void router_kernel(
    const float* __restrict__ X,      // [ntok][H]
    const float* __restrict__ Wd,     // [DBOT][H]
    const float* __restrict__ Wu,     // [NE][DBOT]
    const float* __restrict__ gamma,  // [H]
    const float* __restrict__ beta,   // [H]
    float* __restrict__ out,          // [ntok][NE]
    const int ntok)
{
    __shared__ unsigned short stage[NWAVE * 2 * WVBUF];  // 73728 B; reused as red
    __shared__ float rsumP[NWAVE * 64], rsqP[NWAVE * 64];
    __shared__ float BdS[DBOT], CdS[DBOT];
    __shared__ float wuS[NE * DBOT];

    const int tid  = threadIdx.x;
    const int lane = tid & 63;
    const int wv   = tid >> 6;                 // wave id = K-slice owner
    const long tok0 = (long)blockIdx.x * 64;

    if (tid < 128) ((float4*)wuS)[tid] = ((const float4*)Wu)[tid];

    // ---- Phase 0: B_d = sum gamma*W[d], C_d = sum beta*W[d]
    {
        const int d = tid >> 2, s = tid & 3;
        const float* wr = &Wd[d * H + s * 512];
        const float* gr = &gamma[s * 512];
        const float* br = &beta [s * 512];
        float bp = 0.f, cp = 0.f;
        #pragma unroll 4
        for (int i = 0; i < 512; i += 4) {
            const float4 w4 = *(const float4*)&wr[i];
            const float4 g4 = *(const float4*)&gr[i];
            const float4 b4 = *(const float4*)&br[i];
            bp += (w4.x*g4.x + w4.y*g4.y) + (w4.z*g4.z + w4.w*g4.w);
            cp += (w4.x*b4.x + w4.y*b4.y) + (w4.z*b4.z + w4.w*b4.w);
        }
        bp += __shfl_xor(bp, 1); bp += __shfl_xor(bp, 2);
        cp += __shfl_xor(cp, 1); cp += __shfl_xor(cp, 2);
        if (s == 0) { BdS[d] = bp; CdS[d] = cp; }
    }

    // ---- Main loop (wave-private; no block barriers)
    unsigned short* XB = &stage[wv * 2 * WVBUF];
    unsigned short* WB = XB + WVBUF;

    f32x4 acc[4][4];
    #pragma unroll
    for (int i = 0; i < 4; ++i)
        #pragma unroll
        for (int j = 0; j < 4; ++j) acc[i][j] = (f32x4){0.f, 0.f, 0.f, 0.f};

    float xs[8], xq[8];
    #pragma unroll
    for (int p = 0; p < 8; ++p) { xs[p] = 0.f; xq[p] = 0.f; }

    const int srow = lane >> 3;        // staging row within group of 8
    const int scol = lane & 7;         // float4 column (4 k each)
    const int sg   = scol >> 1;        // 8-k group 0..3
    const int sh   = (scol & 1) * 4;   // half offset in shorts
    const int quad = lane >> 4;        // MFMA k-group
    const int lcol = lane & 15;        // MFMA row-in-tile

    for (int ch = 0; ch < NCH; ++ch) {
        const int kg = wv * KSL + ch * KC;
        const float4 g4 = *(const float4*)&gamma[kg + 4 * scol];

        #pragma unroll
        for (int p = 0; p < 8; ++p) {
            const int r = srow + 8 * p;
            // X row: stats + hi/lo split
            float4 xv = make_float4(0.f, 0.f, 0.f, 0.f);
            if (tok0 + r < ntok)
                xv = *(const float4*)&X[(tok0 + r) * (long)H + kg + 4 * scol];
            xs[p] += (xv.x + xv.y) + (xv.z + xv.w);
            xq[p] += (xv.x*xv.x + xv.y*xv.y) + (xv.z*xv.z + xv.w*xv.w);
            ushort4 h, l;
            h.x = bf16rne(xv.x); h.y = bf16rne(xv.y);
            h.z = bf16rne(xv.z); h.w = bf16rne(xv.w);
            l.x = bf16rne(xv.x - bf16tof(h.x));
            l.y = bf16rne(xv.y - bf16tof(h.y));
            l.z = bf16rne(xv.z - bf16tof(h.z));
            l.w = bf16rne(xv.w - bf16tof(h.w));
            unsigned short* rb = &XB[r * ROWS + sg * 16 + sh];
            *(ushort4*)&rb[0] = h;
            *(ushort4*)&rb[8] = l;

            // W row: gamma fold + hi/lo split
            const float4 w4 = *(const float4*)&Wd[r * (long)H + kg + 4 * scol];
            const float4 wg = make_float4(w4.x*g4.x, w4.y*g4.y, w4.z*g4.z, w4.w*g4.w);
            h.x = bf16rne(wg.x); h.y = bf16rne(wg.y);
            h.z = bf16rne(wg.z); h.w = bf16rne(wg.w);
            l.x = bf16rne(wg.x - bf16tof(h.x));
            l.y = bf16rne(wg.y - bf16tof(h.y));
            l.z = bf16rne(wg.z - bf16tof(h.z));
            l.w = bf16rne(wg.w - bf16tof(h.w));
            unsigned short* wb = &WB[r * ROWS + sg * 16 + sh];
            *(ushort4*)&wb[0] = h;
            *(ushort4*)&wb[8] = l;
        }

        // MFMA: A[m=lcol][k=quad*8+j] layout; tiles ti (token), tj (d)
        bf16x8 Ahi[4], Alo[4];
        #pragma unroll
        for (int ti = 0; ti < 4; ++ti) {
            const unsigned short* ab = &XB[(16*ti + lcol) * ROWS + quad * 16];
            Ahi[ti] = *(const bf16x8*)&ab[0];
            Alo[ti] = *(const bf16x8*)&ab[8];
        }
        #pragma unroll
        for (int tj = 0; tj < 4; ++tj) {
            const unsigned short* bb = &WB[(16*tj + lcol) * ROWS + quad * 16];
            const bf16x8 Bhi = *(const bf16x8*)&bb[0];
            const bf16x8 Blo = *(const bf16x8*)&bb[8];
            #pragma unroll
            for (int ti = 0; ti < 4; ++ti) {
                acc[ti][tj] = __builtin_amdgcn_mfma_f32_16x16x32_bf16(
                    Ahi[ti], Bhi, acc[ti][tj], 0, 0, 0);
                acc[ti][tj] = __builtin_amdgcn_mfma_f32_16x16x32_bf16(
                    Ahi[ti], Blo, acc[ti][tj], 0, 0, 0);
                acc[ti][tj] = __builtin_amdgcn_mfma_f32_16x16x32_bf16(
                    Alo[ti], Bhi, acc[ti][tj], 0, 0, 0);
            }
        }
    }

    // ---- Stats: reduce over the 8 lanes sharing srow (width-8 shuffle)
    #pragma unroll
    for (int p = 0; p < 8; ++p) {
        float s = xs[p], q = xq[p];
        s += __shfl_xor(s, 1); q += __shfl_xor(q, 1);
        s += __shfl_xor(s, 2); q += __shfl_xor(q, 2);
        s += __shfl_xor(s, 4); q += __shfl_xor(q, 4);
        if (scol == 0) {
            rsumP[wv * 64 + srow + 8 * p] = s;
            rsqP [wv * 64 + srow + 8 * p] = q;
        }
    }

    // ---- Combine split-K acc partials in LDS (overlays stage; barrier first)
    float* red = (float*)stage;   // [c][r] fp32, stride RST; 64*68*4 B used
    __syncthreads();              // all waves done with stage buffers
    for (int w = 0; w < NWAVE; ++w) {
        if (wv == w) {
            #pragma unroll
            for (int ti = 0; ti < 4; ++ti)
                #pragma unroll
                for (int tj = 0; tj < 4; ++tj) {
                    const int c  = 16*tj + lcol;
                    const int r0 = 16*ti + 4*quad;   // C: row=(lane>>4)*4+reg
                    f32x4* p = (f32x4*)&red[c * RST + r0];
                    if (w == 0) *p = acc[ti][tj];
                    else {
                        f32x4 v = *p;
                        v += acc[ti][tj];
                        *p = v;
                    }
                }
        }
        __syncthreads();
    }

    // ---- Epilogue: thread (r = tid>>2, cq = tid&3) does 16 d-columns
    {
        const int r  = tid >> 2;
        const int cq = tid & 3;
        const float invH = 1.0f / (float)H;
        const float rsum = rsumP[r] + rsumP[64 + r] + rsumP[128 + r] + rsumP[192 + r];
        const float rsq  = rsqP [r] + rsqP [64 + r] + rsqP [128 + r] + rsqP [192 + r];
        const float mu   = rsum * invH;
        const float var  = rsq * invH - mu * mu;
        const float rstd = 1.0f / sqrtf(var + 1e-5f);

        float lg[NE];
        #pragma unroll
        for (int e = 0; e < NE; ++e) lg[e] = 0.f;
        #pragma unroll
        for (int i = 0; i < 16; ++i) {
            const int c = cq * 16 + i;
            const float A = red[c * RST + r];
            const float t = rstd * (A - mu * BdS[c]) + CdS[c];
            const float z = t / (1.0f + expf(-t));
            #pragma unroll
            for (int e = 0; e < NE; ++e) lg[e] += z * wuS[e * DBOT + c];
        }
        #pragma unroll
        for (int e = 0; e < NE; ++e) {
            lg[e] += __shfl_xor(lg[e], 1);
            lg[e] += __shfl_xor(lg[e], 2);
        }

        if (cq == 0 && tok0 + r < ntok) {
            // top-2; strict > keeps lowest index on ties (matches lax.top_k)
            float v1 = -INFINITY, v2 = -INFINITY;
            int i1 = -1, i2 = -1;
            #pragma unroll
            for (int e = 0; e < NE; ++e) {
                const float v = lg[e];
                if (v > v1)      { v2 = v1; i2 = i1; v1 = v; i1 = e; }
                else if (v > v2) { v2 = v;  i2 = e; }
            }
            const float e2  = expf(v2 - v1);
            const float inv = 1.0f / (1.0f + e2);
            float o[NE];
            #pragma unroll
            for (int e = 0; e < NE; ++e)
                o[e] = (e == i1) ? inv : ((e == i2) ? e2 * inv : 0.0f);
            float4* op = (float4*)&out[(tok0 + r) * NE];
            op[0] = make_float4(o[0], o[1], o[2], o[3]);
            op[1] = make_float4(o[4], o[5], o[6], o[7]);
        }
    }
}

extern "C" void kernel_launch(void* const* d_in, const int* in_sizes, int n_in,
                              void* d_out, int out_size, void* d_ws, size_t ws_size,
                              hipStream_t stream) {
    const float* X     = (const float*)d_in[0];
    const float* Wd    = (const float*)d_in[1];
    const float* Wu    = (const float*)d_in[2];
    const float* gamma = (const float*)d_in[3];
    const float* beta  = (const float*)d_in[4];
    float* out = (float*)d_out;

    const int ntok = in_sizes[0] / H;            // 16384
    const int nblk = (ntok + 63) / 64;           // 256

    hipLaunchKernelGGL(router_kernel, dim3(nblk), dim3(256), 0, stream,
                       X, Wd, Wu, gamma, beta, out, ntok);
}

// Round 6
// 223.687 us; speedup vs baseline: 1.9871x; 1.4187x over previous
//
#include <hip/hip_runtime.h>
#include <math.h>

// TokenRouter: LN(x) -> silu(x @ Wd^T) -> @ Wu^T -> top2 softmax
// H=2048, D=64, E=8, NTOK=16384, fp32 in/out.
//
// R6: bf16x3 MFMA (proven exact in R5) + occupancy fix. R5 was 1 wave/SIMD
// (11% occupancy, all pipes idle). Now: 256 blocks x 1024 thr = 16 waves
// (4/SIMD). Output 64x64 = 16 tiles of 16x16; wave w owns tile
// (ti=w&3, tj=w>>2), accumulates over ALL K (no cross-wave reduction).
// K staged cooperatively, 64-k chunks, double-buffered LDS, 1 barrier/chunk;
// next chunk's global loads issued before frags/MFMA to overlap latency.
// LN folded: dot = rstd*(A - mu*B_d) + C_d. mu/var, B_d, C_d accumulated
// during staging (thread t owns row t>>4; shuffle-16 reduce). No phase 0.
// R4 lesson: no register array indexed by non-unrolled loop var.

#define H     2048
#define DBOT  64
#define NE    8
#define KC    64
#define NCH   (H / KC)     // 32
#define RS    136          // shorts per LDS row: 64 hi | 64 lo | 8 pad (272 B)
#define RST   68           // fp32 combine row stride

typedef short  bf16x8 __attribute__((ext_vector_type(8)));
typedef float  f32x4  __attribute__((ext_vector_type(4)));

__device__ __forceinline__ unsigned short bf16rne(float x) {
    unsigned u = __float_as_uint(x);
    return (unsigned short)((u + 0x7FFFu + ((u >> 16) & 1u)) >> 16);
}
__device__ __forceinline__ float bf16tof(unsigned short h) {
    return __uint_as_float(((unsigned)h) << 16);
}

__global__ __launch_bounds__(1024) void router_kernel(
    const float* __restrict__ X,      // [ntok][H]
    const float* __restrict__ Wd,     // [DBOT][H]
    const float* __restrict__ Wu,     // [NE][DBOT]
    const float* __restrict__ gamma,  // [H]
    const float* __restrict__ beta,   // [H]
    float* __restrict__ out,          // [ntok][NE]
    const int ntok)
{
    __shared__ unsigned short stage[2][2][64 * RS];  // [buf][X|W][row*RS] 69632 B
    __shared__ float rsumS[64], rsqS[64], BdS[64], CdS[64];
    __shared__ float wuS[NE * DBOT];

    const int tid  = threadIdx.x;
    const int lane = tid & 63;
    const int wv   = tid >> 6;        // wave 0..15
    const int ti   = wv & 3;          // token-tile
    const int tj   = wv >> 2;         // d-tile
    const int q    = lane >> 4;       // MFMA k-quad
    const int m    = lane & 15;       // MFMA row/col in tile
    const int r    = tid >> 4;        // staging row 0..63 (token row & d row)
    const int c4   = tid & 15;        // staging float4 column
    const long tok0 = (long)blockIdx.x * 64;

    if (tid < 128) ((float4*)wuS)[tid] = ((const float4*)Wu)[tid];

    const bool  xok  = (tok0 + r) < ntok;
    const float* Xrow = &X[(tok0 + r) * (long)H + 4 * c4];
    const float* Wrow = &Wd[r * (long)H + 4 * c4];

    float xs = 0.f, xq = 0.f, bacc = 0.f, cacc = 0.f;
    f32x4 acc0 = (f32x4){0.f, 0.f, 0.f, 0.f};
    f32x4 acc1 = (f32x4){0.f, 0.f, 0.f, 0.f};

    // convert-and-commit one staged (X,W) float4 pair into buffer `buf`
    auto commit = [&](int buf, float4 xv, float4 wvv, float4 g4, float4 b4) {
        xs += (xv.x + xv.y) + (xv.z + xv.w);
        xq += (xv.x*xv.x + xv.y*xv.y) + (xv.z*xv.z + xv.w*xv.w);
        ushort4 h, l;
        h.x = bf16rne(xv.x); h.y = bf16rne(xv.y);
        h.z = bf16rne(xv.z); h.w = bf16rne(xv.w);
        l.x = bf16rne(xv.x - bf16tof(h.x));
        l.y = bf16rne(xv.y - bf16tof(h.y));
        l.z = bf16rne(xv.z - bf16tof(h.z));
        l.w = bf16rne(xv.w - bf16tof(h.w));
        *(ushort4*)&stage[buf][0][r * RS + 4 * c4]      = h;
        *(ushort4*)&stage[buf][0][r * RS + 64 + 4 * c4] = l;

        const float4 wg = make_float4(wvv.x*g4.x, wvv.y*g4.y, wvv.z*g4.z, wvv.w*g4.w);
        bacc += (wg.x + wg.y) + (wg.z + wg.w);
        cacc += (wvv.x*b4.x + wvv.y*b4.y) + (wvv.z*b4.z + wvv.w*b4.w);
        h.x = bf16rne(wg.x); h.y = bf16rne(wg.y);
        h.z = bf16rne(wg.z); h.w = bf16rne(wg.w);
        l.x = bf16rne(wg.x - bf16tof(h.x));
        l.y = bf16rne(wg.y - bf16tof(h.y));
        l.z = bf16rne(wg.z - bf16tof(h.z));
        l.w = bf16rne(wg.w - bf16tof(h.w));
        *(ushort4*)&stage[buf][1][r * RS + 4 * c4]      = h;
        *(ushort4*)&stage[buf][1][r * RS + 64 + 4 * c4] = l;
    };

    // prologue: stage chunk 0 into buf 0
    {
        const float4 z4 = make_float4(0.f, 0.f, 0.f, 0.f);
        const float4 xv = xok ? *(const float4*)&Xrow[0] : z4;
        const float4 wvv = *(const float4*)&Wrow[0];
        const float4 g4 = *(const float4*)&gamma[4 * c4];
        const float4 b4 = *(const float4*)&beta [4 * c4];
        commit(0, xv, wvv, g4, b4);
    }
    __syncthreads();

    const int abase = (16 * ti + m) * RS + q * 8;  // A frag short-offset
    const int bbase = (16 * tj + m) * RS + q * 8;  // B frag short-offset

    #pragma unroll 2
    for (int ch = 0; ch < NCH; ++ch) {
        const int cur = ch & 1;

        // issue next chunk's global loads FIRST (consumed after MFMA)
        float4 nxv = make_float4(0.f, 0.f, 0.f, 0.f);
        float4 nwv = nxv, ng4 = nxv, nb4 = nxv;
        if (ch + 1 < NCH) {
            const int kn = (ch + 1) * KC;
            if (xok) nxv = *(const float4*)&Xrow[kn];
            nwv = *(const float4*)&Wrow[kn];
            ng4 = *(const float4*)&gamma[kn + 4 * c4];
            nb4 = *(const float4*)&beta [kn + 4 * c4];
        }

        // fragments from current buffer; two k-steps (s=0,1) on two accs
        const unsigned short* XB = stage[cur][0];
        const unsigned short* WB = stage[cur][1];
        const bf16x8 Ah0 = *(const bf16x8*)&XB[abase];
        const bf16x8 Al0 = *(const bf16x8*)&XB[abase + 64];
        const bf16x8 Bh0 = *(const bf16x8*)&WB[bbase];
        const bf16x8 Bl0 = *(const bf16x8*)&WB[bbase + 64];
        const bf16x8 Ah1 = *(const bf16x8*)&XB[abase + 32];
        const bf16x8 Al1 = *(const bf16x8*)&XB[abase + 96];
        const bf16x8 Bh1 = *(const bf16x8*)&WB[bbase + 32];
        const bf16x8 Bl1 = *(const bf16x8*)&WB[bbase + 96];

        acc0 = __builtin_amdgcn_mfma_f32_16x16x32_bf16(Ah0, Bh0, acc0, 0, 0, 0);
        acc1 = __builtin_amdgcn_mfma_f32_16x16x32_bf16(Ah1, Bh1, acc1, 0, 0, 0);
        acc0 = __builtin_amdgcn_mfma_f32_16x16x32_bf16(Ah0, Bl0, acc0, 0, 0, 0);
        acc1 = __builtin_amdgcn_mfma_f32_16x16x32_bf16(Ah1, Bl1, acc1, 0, 0, 0);
        acc0 = __builtin_amdgcn_mfma_f32_16x16x32_bf16(Al0, Bh0, acc0, 0, 0, 0);
        acc1 = __builtin_amdgcn_mfma_f32_16x16x32_bf16(Al1, Bh1, acc1, 0, 0, 0);

        // convert + write next chunk into the other buffer
        if (ch + 1 < NCH) commit(cur ^ 1, nxv, nwv, ng4, nb4);

        __syncthreads();
    }

    // ---- reduce staging-side stats across the 16 threads sharing row r
    {
        float s = xs, sq = xq, b = bacc, c = cacc;
        s  += __shfl_xor(s, 1);  s  += __shfl_xor(s, 2);
        s  += __shfl_xor(s, 4);  s  += __shfl_xor(s, 8);
        sq += __shfl_xor(sq, 1); sq += __shfl_xor(sq, 2);
        sq += __shfl_xor(sq, 4); sq += __shfl_xor(sq, 8);
        b  += __shfl_xor(b, 1);  b  += __shfl_xor(b, 2);
        b  += __shfl_xor(b, 4);  b  += __shfl_xor(b, 8);
        c  += __shfl_xor(c, 1);  c  += __shfl_xor(c, 2);
        c  += __shfl_xor(c, 4);  c  += __shfl_xor(c, 8);
        if (c4 == 0) { rsumS[r] = s; rsqS[r] = sq; BdS[r] = b; CdS[r] = c; }
    }

    // ---- each wave writes its finished 16x16 tile: red[d][token]
    float* red = (float*)stage;   // overlays stage[0][0] (64*68*4 = 17408 B)
    {
        const f32x4 a = acc0 + acc1;
        // C layout: n(col)=lane&15 -> d = 16*tj+m ; m-rows = 4*q + reg -> token
        *(f32x4*)&red[(16 * tj + m) * RST + 16 * ti + 4 * q] = a;
    }
    __syncthreads();

    // ---- epilogue: thread (r=t>>2, cq=t&3) handles 16 d-columns
    if (tid < 256) {
        const int er = tid >> 2;
        const int cq = tid & 3;
        const float invH = 1.0f / (float)H;
        const float mu   = rsumS[er] * invH;
        const float var  = rsqS[er] * invH - mu * mu;
        const float rstd = 1.0f / sqrtf(var + 1e-5f);

        float lg[NE];
        #pragma unroll
        for (int e = 0; e < NE; ++e) lg[e] = 0.f;
        #pragma unroll
        for (int i = 0; i < 16; ++i) {
            const int c = cq * 16 + i;
            const float A = red[c * RST + er];
            const float t = rstd * (A - mu * BdS[c]) + CdS[c];
            const float z = t / (1.0f + expf(-t));
            #pragma unroll
            for (int e = 0; e < NE; ++e) lg[e] += z * wuS[e * DBOT + c];
        }
        #pragma unroll
        for (int e = 0; e < NE; ++e) {
            lg[e] += __shfl_xor(lg[e], 1);
            lg[e] += __shfl_xor(lg[e], 2);
        }

        if (cq == 0 && tok0 + er < ntok) {
            // top-2; strict > keeps lowest index on ties (matches lax.top_k)
            float v1 = -INFINITY, v2 = -INFINITY;
            int i1 = -1, i2 = -1;
            #pragma unroll
            for (int e = 0; e < NE; ++e) {
                const float v = lg[e];
                if (v > v1)      { v2 = v1; i2 = i1; v1 = v; i1 = e; }
                else if (v > v2) { v2 = v;  i2 = e; }
            }
            const float e2  = expf(v2 - v1);
            const float inv = 1.0f / (1.0f + e2);
            float o[NE];
            #pragma unroll
            for (int e = 0; e < NE; ++e)
                o[e] = (e == i1) ? inv : ((e == i2) ? e2 * inv : 0.0f);
            float4* op = (float4*)&out[(tok0 + er) * NE];
            op[0] = make_float4(o[0], o[1], o[2], o[3]);
            op[1] = make_float4(o[4], o[5], o[6], o[7]);
        }
    }
}

extern "C" void kernel_launch(void* const* d_in, const int* in_sizes, int n_in,
                              void* d_out, int out_size, void* d_ws, size_t ws_size,
                              hipStream_t stream) {
    const float* X     = (const float*)d_in[0];
    const float* Wd    = (const float*)d_in[1];
    const float* Wu    = (const float*)d_in[2];
    const float* gamma = (const float*)d_in[3];
    const float* beta  = (const float*)d_in[4];
    float* out = (float*)d_out;

    const int ntok = in_sizes[0] / H;            // 16384
    const int nblk = (ntok + 63) / 64;           // 256

    hipLaunchKernelGGL(router_kernel, dim3(nblk), dim3(1024), 0, stream,
                       X, Wd, Wu, gamma, beta, out, ntok);
}

// Round 7
// 219.286 us; speedup vs baseline: 2.0270x; 1.0201x over previous
//
#include <hip/hip_runtime.h>
#include <math.h>

// TokenRouter: LN(x) -> silu(x @ Wd^T) -> @ Wu^T -> top2 softmax
// H=2048, D=64, E=8, NTOK=16384, fp32 in/out.
//
// R7: 32x32x16 MFMA (2x FLOP per frag-read byte vs 16x16x32) + 2 blocks/CU.
// Block = 32 tokens, 512 thr = 8 waves, grid 512 => 2 blocks/CU (16 waves,
// 50% occ) so one block computes while the other drains its chunk barrier.
// Wave w: k-step s=w>>1 (16-k slice of each 64-k chunk), d-half tj=w&1.
// bf16x3 split (proven exact R5/R6): x*w ~= xh*wh + xh*wl + xl*wh.
// LN folded: dot = rstd*(A - mu*B_d) + C_d; stats/B/C accumulated in staging.
// 4 step-partials per tile combined via LDS; epilogue as R6.
// R4 lesson: register arrays only indexed by unrolled constants.

#define H     2048
#define DBOT  64
#define NE    8
#define NTB   32             // tokens per block
#define KC    64
#define NCH   (H / KC)       // 32
#define RS    136            // shorts per LDS row: 64 hi | 64 lo | 8 pad (272 B)
#define RSTT  36             // f32 combine row stride (32 tok + 4 pad)
#define REDSZ (DBOT * RSTT)  // floats per partial region (2304)

typedef short  bf16x8  __attribute__((ext_vector_type(8)));
typedef float  f32x4   __attribute__((ext_vector_type(4)));
typedef float  f32x16  __attribute__((ext_vector_type(16)));

__device__ __forceinline__ unsigned short bf16rne(float x) {
    unsigned u = __float_as_uint(x);
    return (unsigned short)((u + 0x7FFFu + ((u >> 16) & 1u)) >> 16);
}
__device__ __forceinline__ float bf16tof(unsigned short h) {
    return __uint_as_float(((unsigned)h) << 16);
}

__global__ __launch_bounds__(512, 4) void router_kernel(
    const float* __restrict__ X,      // [ntok][H]
    const float* __restrict__ Wd,     // [DBOT][H]
    const float* __restrict__ Wu,     // [NE][DBOT]
    const float* __restrict__ gamma,  // [H]
    const float* __restrict__ beta,   // [H]
    float* __restrict__ out,          // [ntok][NE]
    const int ntok)
{
    // stage[buf]: rows 0..31 = X tile, rows 32..95 = W tile (gamma-folded)
    __shared__ unsigned short stage[2][96 * RS];   // 52224 B
    __shared__ float rsumS[NTB], rsqS[NTB], BdS[DBOT], CdS[DBOT];
    __shared__ float wuS[NE * DBOT];

    const int tid = threadIdx.x;
    const int xr  = tid >> 4;         // 0..31: X row and W row pair (xr, xr+32)
    const int xc  = tid & 15;         // float4 col, k = 4*xc
    const long tok0 = (long)blockIdx.x * NTB;

    if (tid < 128) ((float4*)wuS)[tid] = ((const float4*)Wu)[tid];

    const bool xok = (tok0 + xr) < ntok;
    const float* Xrow  = &X[(tok0 + xr) * (long)H + 4 * xc];
    const float* Wrow0 = &Wd[xr * (long)H + 4 * xc];
    const float* Wrow1 = &Wd[(xr + 32) * (long)H + 4 * xc];

    float xs = 0.f, xq = 0.f;
    float b0 = 0.f, c0 = 0.f, b1 = 0.f, c1 = 0.f;
    f32x16 acc = {};

    auto commit = [&](int buf, float4 xv, float4 wv0, float4 wv1,
                      float4 g4, float4 b4) {
        unsigned short* XB = &stage[buf][0];
        unsigned short* WB = &stage[buf][NTB * RS];
        ushort4 h, l;
        // X: stats + hi/lo split
        xs += (xv.x + xv.y) + (xv.z + xv.w);
        xq += (xv.x*xv.x + xv.y*xv.y) + (xv.z*xv.z + xv.w*xv.w);
        h.x = bf16rne(xv.x); h.y = bf16rne(xv.y);
        h.z = bf16rne(xv.z); h.w = bf16rne(xv.w);
        l.x = bf16rne(xv.x - bf16tof(h.x));
        l.y = bf16rne(xv.y - bf16tof(h.y));
        l.z = bf16rne(xv.z - bf16tof(h.z));
        l.w = bf16rne(xv.w - bf16tof(h.w));
        *(ushort4*)&XB[xr * RS + 4 * xc]      = h;
        *(ushort4*)&XB[xr * RS + 64 + 4 * xc] = l;
        // W row xr: gamma fold, B/C partials, hi/lo split
        float4 wg = make_float4(wv0.x*g4.x, wv0.y*g4.y, wv0.z*g4.z, wv0.w*g4.w);
        b0 += (wg.x + wg.y) + (wg.z + wg.w);
        c0 += (wv0.x*b4.x + wv0.y*b4.y) + (wv0.z*b4.z + wv0.w*b4.w);
        h.x = bf16rne(wg.x); h.y = bf16rne(wg.y);
        h.z = bf16rne(wg.z); h.w = bf16rne(wg.w);
        l.x = bf16rne(wg.x - bf16tof(h.x));
        l.y = bf16rne(wg.y - bf16tof(h.y));
        l.z = bf16rne(wg.z - bf16tof(h.z));
        l.w = bf16rne(wg.w - bf16tof(h.w));
        *(ushort4*)&WB[xr * RS + 4 * xc]      = h;
        *(ushort4*)&WB[xr * RS + 64 + 4 * xc] = l;
        // W row xr+32
        wg = make_float4(wv1.x*g4.x, wv1.y*g4.y, wv1.z*g4.z, wv1.w*g4.w);
        b1 += (wg.x + wg.y) + (wg.z + wg.w);
        c1 += (wv1.x*b4.x + wv1.y*b4.y) + (wv1.z*b4.z + wv1.w*b4.w);
        h.x = bf16rne(wg.x); h.y = bf16rne(wg.y);
        h.z = bf16rne(wg.z); h.w = bf16rne(wg.w);
        l.x = bf16rne(wg.x - bf16tof(h.x));
        l.y = bf16rne(wg.y - bf16tof(h.y));
        l.z = bf16rne(wg.z - bf16tof(h.z));
        l.w = bf16rne(wg.w - bf16tof(h.w));
        *(ushort4*)&WB[(xr + 32) * RS + 4 * xc]      = h;
        *(ushort4*)&WB[(xr + 32) * RS + 64 + 4 * xc] = l;
    };

    // prologue: chunk 0 -> buf 0
    {
        const float4 z4 = make_float4(0.f, 0.f, 0.f, 0.f);
        const float4 xv  = xok ? *(const float4*)&Xrow[0] : z4;
        const float4 wv0 = *(const float4*)&Wrow0[0];
        const float4 wv1 = *(const float4*)&Wrow1[0];
        const float4 g4  = *(const float4*)&gamma[4 * xc];
        const float4 b4  = *(const float4*)&beta [4 * xc];
        commit(0, xv, wv0, wv1, g4, b4);
    }
    __syncthreads();

    // wave roles: s = k-step (0..3, 16 k each), tj = d-half (0..1)
    const int wv   = tid >> 6;
    const int s    = wv >> 1;
    const int tj   = wv & 1;
    const int ln   = tid & 63;
    const int nrow = ln & 31;            // A: token row / B: d row in tile
    const int kh   = ln >> 5;            // k-half within 16-k step
    const int koff = s * 16 + kh * 8;    // short offset in hi region
    const int abase = nrow * RS + koff;
    const int bbase = (NTB + 32 * tj + nrow) * RS + koff;

    for (int ch = 0; ch < NCH; ++ch) {
        const int cur = ch & 1;

        // prefetch next chunk's globals first
        float4 nxv = make_float4(0.f, 0.f, 0.f, 0.f);
        float4 nwv0 = nxv, nwv1 = nxv, ng4 = nxv, nb4 = nxv;
        if (ch + 1 < NCH) {
            const int kn = (ch + 1) * KC;
            if (xok) nxv = *(const float4*)&Xrow[kn];
            nwv0 = *(const float4*)&Wrow0[kn];
            nwv1 = *(const float4*)&Wrow1[kn];
            ng4  = *(const float4*)&gamma[kn + 4 * xc];
            nb4  = *(const float4*)&beta [kn + 4 * xc];
        }

        const unsigned short* SB = stage[cur];
        const bf16x8 Ah = *(const bf16x8*)&SB[abase];
        const bf16x8 Al = *(const bf16x8*)&SB[abase + 64];
        const bf16x8 Bh = *(const bf16x8*)&SB[bbase];
        const bf16x8 Bl = *(const bf16x8*)&SB[bbase + 64];

        acc = __builtin_amdgcn_mfma_f32_32x32x16_bf16(Ah, Bh, acc, 0, 0, 0);
        acc = __builtin_amdgcn_mfma_f32_32x32x16_bf16(Ah, Bl, acc, 0, 0, 0);
        acc = __builtin_amdgcn_mfma_f32_32x32x16_bf16(Al, Bh, acc, 0, 0, 0);

        if (ch + 1 < NCH) commit(cur ^ 1, nxv, nwv0, nwv1, ng4, nb4);
        __syncthreads();
    }

    // ---- stats: reduce over 16 consecutive lanes sharing xr
    {
        float s1 = xs, s2 = xq, s3 = b0, s4 = c0, s5 = b1, s6 = c1;
        #pragma unroll
        for (int m = 1; m < 16; m <<= 1) {
            s1 += __shfl_xor(s1, m); s2 += __shfl_xor(s2, m);
            s3 += __shfl_xor(s3, m); s4 += __shfl_xor(s4, m);
            s5 += __shfl_xor(s5, m); s6 += __shfl_xor(s6, m);
        }
        if (xc == 0) {
            rsumS[xr] = s1; rsqS[xr] = s2;
            BdS[xr] = s3;  CdS[xr] = s4;
            BdS[xr + 32] = s5; CdS[xr + 32] = s6;
        }
    }

    // ---- write step-partials: red[s][d*RSTT + token] (overlays stage)
    float* red = (float*)stage;
    {
        const int d = 32 * tj + nrow;
        float* rp = &red[s * REDSZ + d * RSTT + 4 * kh];
        // C layout: col=lane&31 (=d), row = (reg&3) + 8*(reg>>2) + 4*kh
        const f32x4 v0 = {acc[0],  acc[1],  acc[2],  acc[3]};
        const f32x4 v1 = {acc[4],  acc[5],  acc[6],  acc[7]};
        const f32x4 v2 = {acc[8],  acc[9],  acc[10], acc[11]};
        const f32x4 v3 = {acc[12], acc[13], acc[14], acc[15]};
        *(f32x4*)&rp[0]  = v0;
        *(f32x4*)&rp[8]  = v1;
        *(f32x4*)&rp[16] = v2;
        *(f32x4*)&rp[24] = v3;
    }
    __syncthreads();

    // ---- epilogue: token = tid>>4, 16 threads/token, 4 d-cols each
    {
        const int tok = tid >> 4;
        const int cq  = tid & 15;
        const float invH = 1.0f / (float)H;
        const float mu   = rsumS[tok] * invH;
        const float var  = rsqS[tok] * invH - mu * mu;
        const float rstd = 1.0f / sqrtf(var + 1e-5f);

        float lg[NE];
        #pragma unroll
        for (int e = 0; e < NE; ++e) lg[e] = 0.f;
        #pragma unroll
        for (int i = 0; i < 4; ++i) {
            const int d = 4 * cq + i;
            const float A = red[d * RSTT + tok]
                          + red[REDSZ + d * RSTT + tok]
                          + red[2 * REDSZ + d * RSTT + tok]
                          + red[3 * REDSZ + d * RSTT + tok];
            const float t = rstd * (A - mu * BdS[d]) + CdS[d];
            const float z = t / (1.0f + expf(-t));
            #pragma unroll
            for (int e = 0; e < NE; ++e) lg[e] += z * wuS[e * DBOT + d];
        }
        #pragma unroll
        for (int e = 0; e < NE; ++e) {
            lg[e] += __shfl_xor(lg[e], 1);
            lg[e] += __shfl_xor(lg[e], 2);
            lg[e] += __shfl_xor(lg[e], 4);
            lg[e] += __shfl_xor(lg[e], 8);
        }

        if (cq == 0 && tok0 + tok < ntok) {
            // top-2; strict > keeps lowest index on ties (matches lax.top_k)
            float v1 = -INFINITY, v2 = -INFINITY;
            int i1 = -1, i2 = -1;
            #pragma unroll
            for (int e = 0; e < NE; ++e) {
                const float v = lg[e];
                if (v > v1)      { v2 = v1; i2 = i1; v1 = v; i1 = e; }
                else if (v > v2) { v2 = v;  i2 = e; }
            }
            const float e2  = expf(v2 - v1);
            const float inv = 1.0f / (1.0f + e2);
            float o[NE];
            #pragma unroll
            for (int e = 0; e < NE; ++e)
                o[e] = (e == i1) ? inv : ((e == i2) ? e2 * inv : 0.0f);
            float4* op = (float4*)&out[(tok0 + tok) * NE];
            op[0] = make_float4(o[0], o[1], o[2], o[3]);
            op[1] = make_float4(o[4], o[5], o[6], o[7]);
        }
    }
}

extern "C" void kernel_launch(void* const* d_in, const int* in_sizes, int n_in,
                              void* d_out, int out_size, void* d_ws, size_t ws_size,
                              hipStream_t stream) {
    const float* X     = (const float*)d_in[0];
    const float* Wd    = (const float*)d_in[1];
    const float* Wu    = (const float*)d_in[2];
    const float* gamma = (const float*)d_in[3];
    const float* beta  = (const float*)d_in[4];
    float* out = (float*)d_out;

    const int ntok = in_sizes[0] / H;            // 16384
    const int nblk = (ntok + NTB - 1) / NTB;     // 512

    hipLaunchKernelGGL(router_kernel, dim3(nblk), dim3(512), 0, stream,
                       X, Wd, Wu, gamma, beta, out, ntok);
}

// Round 8
// 211.480 us; speedup vs baseline: 2.1018x; 1.0369x over previous
//
#include <hip/hip_runtime.h>
#include <math.h>

// TokenRouter: LN(x) -> silu(x @ Wd^T) -> @ Wu^T -> top2 softmax
// H=2048, D=64, E=8, NTOK=16384, fp32 in/out.
//
// R8: two-kernel, zero-barrier main loop.
//  prep_kernel: W' = gamma-folded Wd as bf16 hi/lo in d_ws, laid out as
//    ready-to-load MFMA B fragments; also B_d = sum gamma*W, C_d = sum beta*W.
//  router_kernel: NO LDS / NO barriers in the K loop. A operand of
//    mfma_32x32x16_bf16 is lane-contiguous in k (A[m=ln&31][k=(ln>>5)*8+j]),
//    so X is loaded global->VGPR (2 float4/step), hi/lo split in regs, MFMA'd
//    against preconverted B frags from ws. bf16x3: x*w ~= xh*wh+xh*wl+xl*wh
//    (proven exact R5-R7). K split 8 ways across waves -> 4096 waves device-
//    wide (4/SIMD at 2 blocks/CU); 8 partials + stats combined once in LDS.
//  LN folded: dot = rstd*(A - mu*B_d) + C_d; mu/var from X during convert.
//  R4 lesson: register arrays indexed only by unrolled constants.

#define H     2048
#define DBOT  64
#define NE    8
#define NTB   32              // tokens per block (one 32x32 A tile)
#define SPLIT 8               // K-split across waves
#define KSL   (H / SPLIT)     // 256 k per wave
#define NST   (KSL / 16)      // 16 MFMA k-steps per wave
#define RSTT  36              // combine row stride (32 tok + 4 pad)
#define WP_SHORTS (DBOT * H * 2)   // 262144 shorts = 512 KB

typedef short  bf16x8  __attribute__((ext_vector_type(8)));
typedef float  f32x4   __attribute__((ext_vector_type(4)));
typedef float  f32x16  __attribute__((ext_vector_type(16)));

__device__ __forceinline__ unsigned short bf16rne(float x) {
    unsigned u = __float_as_uint(x);
    return (unsigned short)((u + 0x7FFFu + ((u >> 16) & 1u)) >> 16);
}
__device__ __forceinline__ float bf16tof(unsigned short h) {
    return __uint_as_float(((unsigned)h) << 16);
}
// flat short index of the 8-short B-frag group (s,t,tj,hilo,kh,row n)
__device__ __forceinline__ int wp_idx(int s, int t, int tj, int hilo,
                                      int kh, int n) {
    return ((((((s * NST + t) * 2 + tj) * 2 + hilo) * 2 + kh) << 5) + n) << 3;
}

// ---------------- Kernel 1: preconvert W ----------------
__global__ __launch_bounds__(256) void prep_kernel(
    const float* __restrict__ Wd,     // [DBOT][H]
    const float* __restrict__ gamma,  // [H]
    const float* __restrict__ beta,   // [H]
    unsigned short* __restrict__ Wp,  // [WP_SHORTS]
    float* __restrict__ Bd,           // [DBOT]
    float* __restrict__ Cd)           // [DBOT]
{
    __shared__ float bred[4], cred[4];
    const int d   = blockIdx.x;
    const int tid = threadIdx.x;
    const int k0  = tid * 8;                   // 8 consecutive k, 8-aligned
    const int s   = k0 >> 8;
    const int t   = (k0 >> 4) & 15;
    const int kh  = (k0 >> 3) & 1;
    const int tj  = d >> 5;
    const int n   = d & 31;

    const float4 w0 = *(const float4*)&Wd[d * H + k0];
    const float4 w1 = *(const float4*)&Wd[d * H + k0 + 4];
    const float4 g0 = *(const float4*)&gamma[k0];
    const float4 g1 = *(const float4*)&gamma[k0 + 4];
    const float4 b0 = *(const float4*)&beta [k0];
    const float4 b1 = *(const float4*)&beta [k0 + 4];

    const float wg0 = w0.x * g0.x, wg1 = w0.y * g0.y;
    const float wg2 = w0.z * g0.z, wg3 = w0.w * g0.w;
    const float wg4 = w1.x * g1.x, wg5 = w1.y * g1.y;
    const float wg6 = w1.z * g1.z, wg7 = w1.w * g1.w;

    float bp = ((wg0 + wg1) + (wg2 + wg3)) + ((wg4 + wg5) + (wg6 + wg7));
    float cp = ((w0.x*b0.x + w0.y*b0.y) + (w0.z*b0.z + w0.w*b0.w))
             + ((w1.x*b1.x + w1.y*b1.y) + (w1.z*b1.z + w1.w*b1.w));

    ushort4 h0, h1, l0, l1;
    h0.x = bf16rne(wg0); h0.y = bf16rne(wg1);
    h0.z = bf16rne(wg2); h0.w = bf16rne(wg3);
    h1.x = bf16rne(wg4); h1.y = bf16rne(wg5);
    h1.z = bf16rne(wg6); h1.w = bf16rne(wg7);
    l0.x = bf16rne(wg0 - bf16tof(h0.x));
    l0.y = bf16rne(wg1 - bf16tof(h0.y));
    l0.z = bf16rne(wg2 - bf16tof(h0.z));
    l0.w = bf16rne(wg3 - bf16tof(h0.w));
    l1.x = bf16rne(wg4 - bf16tof(h1.x));
    l1.y = bf16rne(wg5 - bf16tof(h1.y));
    l1.z = bf16rne(wg6 - bf16tof(h1.z));
    l1.w = bf16rne(wg7 - bf16tof(h1.w));

    const int ih = wp_idx(s, t, tj, 0, kh, n);
    const int il = wp_idx(s, t, tj, 1, kh, n);
    *(ushort4*)&Wp[ih]     = h0;
    *(ushort4*)&Wp[ih + 4] = h1;
    *(ushort4*)&Wp[il]     = l0;
    *(ushort4*)&Wp[il + 4] = l1;

    // block-reduce bp/cp (4 waves)
    #pragma unroll
    for (int m = 1; m < 64; m <<= 1) {
        bp += __shfl_xor(bp, m);
        cp += __shfl_xor(cp, m);
    }
    if ((tid & 63) == 0) { bred[tid >> 6] = bp; cred[tid >> 6] = cp; }
    __syncthreads();
    if (tid == 0) {
        Bd[d] = (bred[0] + bred[1]) + (bred[2] + bred[3]);
        Cd[d] = (cred[0] + cred[1]) + (cred[2] + cred[3]);
    }
}

// ---------------- Kernel 2: main ----------------
__global__ __launch_bounds__(512, 4) void router_kernel(
    const float* __restrict__ X,            // [ntok][H]
    const unsigned short* __restrict__ Wp,  // preconverted W
    const float* __restrict__ Wu,           // [NE][DBOT]
    const float* __restrict__ Bd,
    const float* __restrict__ Cd,
    float* __restrict__ out,                // [ntok][NE]
    const int ntok)
{
    __shared__ float red[SPLIT * DBOT * RSTT];   // 73728 B
    __shared__ float xsS[SPLIT][NTB], xqS[SPLIT][NTB];
    __shared__ float wuS[NE * DBOT];
    __shared__ float BdS[DBOT], CdS[DBOT];

    const int tid = threadIdx.x;
    const int s   = tid >> 6;        // wave = K-slice owner
    const int ln  = tid & 63;
    const int n   = ln & 31;         // A: token row / B: d row in tile
    const int kh  = ln >> 5;         // k-half within 16-k step
    const long tok0 = (long)blockIdx.x * NTB;

    if (tid < 128) ((float4*)wuS)[tid] = ((const float4*)Wu)[tid];
    if (tid < 64)  { BdS[tid] = Bd[tid]; CdS[tid] = Cd[tid]; }

    const bool xok = (tok0 + n) < ntok;
    const float* Xr = &X[(tok0 + n) * (long)H + s * KSL + kh * 8];
    const unsigned short* WpB = &Wp[wp_idx(s, 0, 0, 0, kh, n)];
    // per-step advance in shorts between t and t+1:
    const int wstep = wp_idx(0, 1, 0, 0, 0, 0);          // = 2*2*2*32*8 = 2048
    const int oB01  = wp_idx(0, 0, 0, 1, 0, 0);          // hilo stride = 512
    const int oB10  = wp_idx(0, 0, 1, 0, 0, 0);          // tj stride  = 1024

    f32x16 acc0 = {}, acc1 = {};
    float xs = 0.f, xq = 0.f;

    const float4 z4 = make_float4(0.f, 0.f, 0.f, 0.f);
    float4 xa = xok ? *(const float4*)&Xr[0] : z4;
    float4 xb = xok ? *(const float4*)&Xr[4] : z4;
    bf16x8 B00 = *(const bf16x8*)&WpB[0];
    bf16x8 B01 = *(const bf16x8*)&WpB[oB01];
    bf16x8 B10 = *(const bf16x8*)&WpB[oB10];
    bf16x8 B11 = *(const bf16x8*)&WpB[oB10 + oB01];

    #pragma unroll 2
    for (int t = 0; t < NST; ++t) {
        // prefetch t+1
        float4 nxa = z4, nxb = z4;
        bf16x8 nB00 = {}, nB01 = {}, nB10 = {}, nB11 = {};
        if (t + 1 < NST) {
            if (xok) {
                nxa = *(const float4*)&Xr[(t + 1) * 16];
                nxb = *(const float4*)&Xr[(t + 1) * 16 + 4];
            }
            const unsigned short* wp = &WpB[(t + 1) * wstep];
            nB00 = *(const bf16x8*)&wp[0];
            nB01 = *(const bf16x8*)&wp[oB01];
            nB10 = *(const bf16x8*)&wp[oB10];
            nB11 = *(const bf16x8*)&wp[oB10 + oB01];
        }

        // stats + hi/lo convert of current X (8 values)
        xs += ((xa.x + xa.y) + (xa.z + xa.w)) + ((xb.x + xb.y) + (xb.z + xb.w));
        xq += ((xa.x*xa.x + xa.y*xa.y) + (xa.z*xa.z + xa.w*xa.w))
            + ((xb.x*xb.x + xb.y*xb.y) + (xb.z*xb.z + xb.w*xb.w));
        bf16x8 Ah, Al;
        Ah[0] = (short)bf16rne(xa.x); Ah[1] = (short)bf16rne(xa.y);
        Ah[2] = (short)bf16rne(xa.z); Ah[3] = (short)bf16rne(xa.w);
        Ah[4] = (short)bf16rne(xb.x); Ah[5] = (short)bf16rne(xb.y);
        Ah[6] = (short)bf16rne(xb.z); Ah[7] = (short)bf16rne(xb.w);
        Al[0] = (short)bf16rne(xa.x - bf16tof((unsigned short)Ah[0]));
        Al[1] = (short)bf16rne(xa.y - bf16tof((unsigned short)Ah[1]));
        Al[2] = (short)bf16rne(xa.z - bf16tof((unsigned short)Ah[2]));
        Al[3] = (short)bf16rne(xa.w - bf16tof((unsigned short)Ah[3]));
        Al[4] = (short)bf16rne(xb.x - bf16tof((unsigned short)Ah[4]));
        Al[5] = (short)bf16rne(xb.y - bf16tof((unsigned short)Ah[5]));
        Al[6] = (short)bf16rne(xb.z - bf16tof((unsigned short)Ah[6]));
        Al[7] = (short)bf16rne(xb.w - bf16tof((unsigned short)Ah[7]));

        acc0 = __builtin_amdgcn_mfma_f32_32x32x16_bf16(Ah, B00, acc0, 0, 0, 0);
        acc1 = __builtin_amdgcn_mfma_f32_32x32x16_bf16(Ah, B10, acc1, 0, 0, 0);
        acc0 = __builtin_amdgcn_mfma_f32_32x32x16_bf16(Ah, B01, acc0, 0, 0, 0);
        acc1 = __builtin_amdgcn_mfma_f32_32x32x16_bf16(Ah, B11, acc1, 0, 0, 0);
        acc0 = __builtin_amdgcn_mfma_f32_32x32x16_bf16(Al, B00, acc0, 0, 0, 0);
        acc1 = __builtin_amdgcn_mfma_f32_32x32x16_bf16(Al, B10, acc1, 0, 0, 0);

        xa = nxa; xb = nxb;
        B00 = nB00; B01 = nB01; B10 = nB10; B11 = nB11;
    }

    // ---- stats: fold kh pair, write wave partials
    xs += __shfl_xor(xs, 32);
    xq += __shfl_xor(xq, 32);
    if (ln < 32) { xsS[s][n] = xs; xqS[s][n] = xq; }

    // ---- write per-wave C partials: red[(s*64 + d)*RSTT + token_row]
    {
        float* rp0 = &red[(s * DBOT + n) * RSTT + 4 * kh];        // tj=0: d=n
        float* rp1 = &red[(s * DBOT + 32 + n) * RSTT + 4 * kh];   // tj=1
        const f32x4 a0 = {acc0[0],  acc0[1],  acc0[2],  acc0[3]};
        const f32x4 a1 = {acc0[4],  acc0[5],  acc0[6],  acc0[7]};
        const f32x4 a2 = {acc0[8],  acc0[9],  acc0[10], acc0[11]};
        const f32x4 a3 = {acc0[12], acc0[13], acc0[14], acc0[15]};
        *(f32x4*)&rp0[0]  = a0;
        *(f32x4*)&rp0[8]  = a1;
        *(f32x4*)&rp0[16] = a2;
        *(f32x4*)&rp0[24] = a3;
        const f32x4 b0 = {acc1[0],  acc1[1],  acc1[2],  acc1[3]};
        const f32x4 b1 = {acc1[4],  acc1[5],  acc1[6],  acc1[7]};
        const f32x4 b2 = {acc1[8],  acc1[9],  acc1[10], acc1[11]};
        const f32x4 b3 = {acc1[12], acc1[13], acc1[14], acc1[15]};
        *(f32x4*)&rp1[0]  = b0;
        *(f32x4*)&rp1[8]  = b1;
        *(f32x4*)&rp1[16] = b2;
        *(f32x4*)&rp1[24] = b3;
    }
    __syncthreads();

    // ---- epilogue: token = tid>>4; 16 threads/token; d = cq + 16*i
    {
        const int tok = tid >> 4;
        const int cq  = tid & 15;
        const float invH = 1.0f / (float)H;
        const float rsum = ((xsS[0][tok] + xsS[1][tok]) + (xsS[2][tok] + xsS[3][tok]))
                         + ((xsS[4][tok] + xsS[5][tok]) + (xsS[6][tok] + xsS[7][tok]));
        const float rsq  = ((xqS[0][tok] + xqS[1][tok]) + (xqS[2][tok] + xqS[3][tok]))
                         + ((xqS[4][tok] + xqS[5][tok]) + (xqS[6][tok] + xqS[7][tok]));
        const float mu   = rsum * invH;
        const float var  = rsq * invH - mu * mu;
        const float rstd = 1.0f / sqrtf(var + 1e-5f);

        float lg[NE];
        #pragma unroll
        for (int e = 0; e < NE; ++e) lg[e] = 0.f;
        #pragma unroll
        for (int i = 0; i < 4; ++i) {
            const int d = cq + 16 * i;
            const float A = (((red[(0*DBOT + d)*RSTT + tok] + red[(1*DBOT + d)*RSTT + tok])
                            + (red[(2*DBOT + d)*RSTT + tok] + red[(3*DBOT + d)*RSTT + tok]))
                           + ((red[(4*DBOT + d)*RSTT + tok] + red[(5*DBOT + d)*RSTT + tok])
                            + (red[(6*DBOT + d)*RSTT + tok] + red[(7*DBOT + d)*RSTT + tok])));
            const float t = rstd * (A - mu * BdS[d]) + CdS[d];
            const float z = t / (1.0f + expf(-t));
            #pragma unroll
            for (int e = 0; e < NE; ++e) lg[e] += z * wuS[e * DBOT + d];
        }
        #pragma unroll
        for (int e = 0; e < NE; ++e) {
            lg[e] += __shfl_xor(lg[e], 1);
            lg[e] += __shfl_xor(lg[e], 2);
            lg[e] += __shfl_xor(lg[e], 4);
            lg[e] += __shfl_xor(lg[e], 8);
        }

        if (cq == 0 && tok0 + tok < ntok) {
            // top-2; strict > keeps lowest index on ties (matches lax.top_k)
            float v1 = -INFINITY, v2 = -INFINITY;
            int i1 = -1, i2 = -1;
            #pragma unroll
            for (int e = 0; e < NE; ++e) {
                const float v = lg[e];
                if (v > v1)      { v2 = v1; i2 = i1; v1 = v; i1 = e; }
                else if (v > v2) { v2 = v;  i2 = e; }
            }
            const float e2  = expf(v2 - v1);
            const float inv = 1.0f / (1.0f + e2);
            float o[NE];
            #pragma unroll
            for (int e = 0; e < NE; ++e)
                o[e] = (e == i1) ? inv : ((e == i2) ? e2 * inv : 0.0f);
            float4* op = (float4*)&out[(tok0 + tok) * NE];
            op[0] = make_float4(o[0], o[1], o[2], o[3]);
            op[1] = make_float4(o[4], o[5], o[6], o[7]);
        }
    }
}

extern "C" void kernel_launch(void* const* d_in, const int* in_sizes, int n_in,
                              void* d_out, int out_size, void* d_ws, size_t ws_size,
                              hipStream_t stream) {
    const float* X     = (const float*)d_in[0];
    const float* Wd    = (const float*)d_in[1];
    const float* Wu    = (const float*)d_in[2];
    const float* gamma = (const float*)d_in[3];
    const float* beta  = (const float*)d_in[4];
    float* out = (float*)d_out;

    unsigned short* Wp = (unsigned short*)d_ws;                 // 512 KB
    float* Bd = (float*)((char*)d_ws + WP_SHORTS * sizeof(short));
    float* Cd = Bd + DBOT;

    const int ntok = in_sizes[0] / H;              // 16384
    const int nblk = (ntok + NTB - 1) / NTB;       // 512

    hipLaunchKernelGGL(prep_kernel, dim3(DBOT), dim3(256), 0, stream,
                       Wd, gamma, beta, Wp, Bd, Cd);
    hipLaunchKernelGGL(router_kernel, dim3(nblk), dim3(512), 0, stream,
                       X, Wp, Wu, Bd, Cd, out, ntok);
}